// Round 6
// baseline (2025.985 us; speedup 1.0000x reference)
//
#include <hip/hip_runtime.h>
#include <type_traits>

namespace {

constexpr int KK   = 7;
constexpr int PADC = 3;
constexpr int B = 8, C = 64, T = 32, H = 56, W = 56;

constexpr int ROWS = 8;                      // output rows per block
constexpr int HALF = 448;                    // threads per channel-half
constexpr int NTHR = 896;                    // 2 halves x (7 dy * 8 chunks * 8 rows)
constexpr int NBLK = B * T * (H / ROWS);     // 1792
constexpr int CH   = 32;                     // channels per half

// LDS layout (floats)
constexpr int X2_STRIDE = 132;               // 8 chunks*16 + 4 pad
constexpr int X2_ROWS   = ROWS + KK - 1;     // 14
constexpr int X2_SIZE   = X2_ROWS * X2_STRIDE;   // 1848
constexpr int X1_STRIDE = 68;                // 8 chunks*8 + 4 pad
constexpr int X1_SIZE   = ROWS * X1_STRIDE;  // 544
constexpr int CBUF      = X2_SIZE + X1_SIZE; // 2392 floats per channel
constexpr int W_SIZE    = C * 56;            // [c][dy*8+j], 3584
// weights + 2 halves x double-buffered channel buffer
constexpr int SMEM_FLOATS = W_SIZE + 4 * CBUF;   // 13152 floats = 52.6 KB

// Counted barrier: make LDS traffic visible without draining vmcnt.
__device__ inline void barrier_lgkm_only() {
  asm volatile("s_waitcnt lgkmcnt(0)" ::: "memory");
  __builtin_amdgcn_s_barrier();
  asm volatile("" ::: "memory");
}

__global__ __launch_bounds__(NTHR)
void corr_fwd(const float* __restrict__ x, const float* __restrict__ fw,
              float* __restrict__ out) {
  __shared__ float smem[SMEM_FLOATS];
  float* w_s = smem;

  const int tid  = threadIdx.x;
  const int cg   = (tid >= HALF) ? 1 : 0;    // channel-half: waves 0-6 / 7-13
  const int ltid = tid - cg * HALF;
  const int dy   = ltid % 7;
  const int q    = (ltid / 7) % 8;
  const int r    = ltid / 56;

  int blk = blockIdx.x;
  const int rt = blk % (H / ROWS);
  blk /= (H / ROWS);
  const int t = blk % T;
  const int b = blk / T;
  const int h0 = rt * ROWS;
  const int tp = (t > 0) ? (t - 1) : 0;

  // ---- stage weights * (1/64) for all c, padded to 8 per (c,dy) row ----
  for (int sid = tid; sid < W_SIZE; sid += NTHR) {
    const int c   = sid / 56;
    const int rm  = sid - c * 56;
    const int dyw = rm >> 3;
    const int j   = rm & 7;
    float v = 0.f;
    if (j < 7) v = fw[((c * T + t) * KK + dyw) * KK + j] * (1.0f / 64.0f);
    w_s[sid] = v;
  }
  // ---- zero-init channel buffers once: halo slots rely on staying 0 ----
  for (int i = tid; i < 4 * CBUF; i += NTHR) smem[W_SIZE + i] = 0.f;

  // ---- staging coordinates (per half, hoisted); l<0 means "skip write" ----
  int g2[4], l2[4];
#pragma unroll
  for (int k = 0; k < 4; ++k) {
    const int sid = ltid + k * HALF;
    const int rr  = sid >> 7;
    const int qq  = (sid >> 4) & 7;
    const int j   = sid & 15;
    const int hg  = h0 + rr - PADC;
    const int wg  = qq * 7 + j - PADC;
    const bool ok = (hg >= 0) && (hg < H) && (wg >= 0) && (wg < W);
    g2[k] = ok ? (hg * W + wg) : 0;
    l2[k] = ok ? (rr * X2_STRIDE + qq * 16 + j) : -1;
  }
  int g1a, l1a;
  {
    const int rr = ltid >> 6, qq = (ltid >> 3) & 7, j = ltid & 7;
    const int wg = qq * 7 + j;
    g1a = (wg < W) ? ((h0 + rr) * W + wg) : 0;
    l1a = (wg < W) ? (rr * X1_STRIDE + qq * 8 + j) : -1;
  }
  const bool hasB = (ltid < 512 - HALF);     // wave 0 of each half: uniform
  int g1b = 0, l1b = -1;
  if (hasB) {
    const int sid = ltid + HALF;
    const int rr = sid >> 6, qq = (sid >> 3) & 7, j = sid & 7;
    const int wg = qq * 7 + j;
    g1b = (wg < W) ? ((h0 + rr) * W + wg) : 0;
    l1b = (wg < W) ? (rr * X1_STRIDE + qq * 8 + j) : -1;
  }

  float acc[7][7];
#pragma unroll
  for (int a = 0; a < 7; ++a)
#pragma unroll
    for (int e = 0; e < 7; ++e) acc[a][e] = 0.f;

  const size_t slice   = (size_t)H * W;        // 3136
  const size_t cstride = (size_t)T * slice;    // 100352
  // this half's channel range starts at cg*CH
  const float* n2 = x + ((size_t)(b * C + cg * CH) * T + t)  * slice;
  const float* n1 = x + ((size_t)(b * C + cg * CH) * T + tp) * slice;

  // ---- 3 register staging sets, 1 channel each (depth-3 SW pipeline) ----
  float S2[3][4], S1A[3], S1B[3];

  auto load_set = [&](auto SC) {
    constexpr int S = decltype(SC)::value;
#pragma unroll
    for (int k = 0; k < 4; ++k) S2[S][k] = n2[g2[k]];
    S1A[S] = n1[g1a];
    if (hasB) S1B[S] = n1[g1b];
    n2 += cstride;
    n1 += cstride;
  };
  auto write_set = [&](auto SC, float* x2s) {
    constexpr int S = decltype(SC)::value;
    float* x1s = x2s + X2_SIZE;
#pragma unroll
    for (int k = 0; k < 4; ++k)
      if (l2[k] >= 0) x2s[l2[k]] = S2[S][k];
    if (l1a >= 0) x1s[l1a] = S1A[S];
    if (hasB && l1b >= 0) x1s[l1b] = S1B[S];
  };
  auto compute1 = [&](const float* x2s, int c) {   // c = within-half channel
    const float* x1s = x2s + X2_SIZE;
    const float4* zp = reinterpret_cast<const float4*>(x2s + (r + dy) * X2_STRIDE + q * 16);
    const float4 z0 = zp[0], z1 = zp[1], z2v = zp[2], z3v = zp[3];
    const float4* xp = reinterpret_cast<const float4*>(x1s + r * X1_STRIDE + q * 8);
    const float4 xa = xp[0], xbv = xp[1];
    const float4* wp = reinterpret_cast<const float4*>(w_s + (cg * CH + c) * 56 + dy * 8);
    const float4 wa = wp[0], wbv = wp[1];

    const float zz[16] = {z0.x, z0.y, z0.z, z0.w,  z1.x, z1.y, z1.z, z1.w,
                          z2v.x, z2v.y, z2v.z, z2v.w,  z3v.x, z3v.y, z3v.z, z3v.w};
    const float xx[7]  = {xa.x, xa.y, xa.z, xa.w,  xbv.x, xbv.y, xbv.z};
    const float wv[7]  = {wa.x, wa.y, wa.z, wa.w,  wbv.x, wbv.y, wbv.z};

#pragma unroll
    for (int i = 0; i < 7; ++i)
#pragma unroll
      for (int dx = 0; dx < 7; ++dx)
        acc[dx][i] = fmaf(wv[dx], xx[i] * zz[i + dx], acc[dx][i]);
  };

  float* hbase = smem + W_SIZE + cg * (2 * CBUF);  // this half's buffers
  float* buf0 = hbase;
  float* buf1 = hbase + CBUF;

  auto stage = [&](auto SC, float* base, int c, bool doLoad) {
    write_set(SC, base);
    if (doLoad) load_set(SC);
    barrier_lgkm_only();
    compute1(base, c);
  };

  __syncthreads();  // zero-init + weights visible before first ds_writes

  // prologue: within-half channels 0,1,2
  load_set(std::integral_constant<int, 0>{});
  load_set(std::integral_constant<int, 1>{});
  load_set(std::integral_constant<int, 2>{});

  // stages 0..23 (all prefetch c+3 <= 26 valid)
  for (int bs = 0; bs < 24; bs += 6) {
    stage(std::integral_constant<int, 0>{}, buf0, bs + 0, true);
    stage(std::integral_constant<int, 1>{}, buf1, bs + 1, true);
    stage(std::integral_constant<int, 2>{}, buf0, bs + 2, true);
    stage(std::integral_constant<int, 0>{}, buf1, bs + 3, true);
    stage(std::integral_constant<int, 1>{}, buf0, bs + 4, true);
    stage(std::integral_constant<int, 2>{}, buf1, bs + 5, true);
  }
  // tail: stages 24..31 (prefetch while c+3 <= 31)
  stage(std::integral_constant<int, 0>{}, buf0, 24, true);   // loads 27
  stage(std::integral_constant<int, 1>{}, buf1, 25, true);   // loads 28
  stage(std::integral_constant<int, 2>{}, buf0, 26, true);   // loads 29
  stage(std::integral_constant<int, 0>{}, buf1, 27, true);   // loads 30
  stage(std::integral_constant<int, 1>{}, buf0, 28, true);   // loads 31
  stage(std::integral_constant<int, 2>{}, buf1, 29, false);
  stage(std::integral_constant<int, 0>{}, buf0, 30, false);
  stage(std::integral_constant<int, 1>{}, buf1, 31, false);

  // ---- epilogue: per-half LDS transpose + 2-term reduce, coalesced out ----
  float* obuf0 = smem;          // alias weights (3584 >= 3136)
  float* obuf1 = smem + 8000;   // alias buffer region (8000+3136 <= 13152)
#pragma unroll 1
  for (int ph = 0; ph < 7; ++ph) {
    __syncthreads();            // full barrier: prior reads/copies retired
    if (dy == ph) {
      float* ob = cg ? obuf1 : obuf0;
#pragma unroll
      for (int dx = 0; dx < 7; ++dx)
#pragma unroll
        for (int i = 0; i < 7; ++i)
          ob[dx * (ROWS * W) + r * W + q * 7 + i] = acc[dx][i];
    }
    __syncthreads();
#pragma unroll
    for (int mi = 0; mi < 4; ++mi) {
      const int m = tid + mi * NTHR;
      if (m < 7 * ROWS * W) {
        const int dxl = m / (ROWS * W);
        const int pos = m - dxl * (ROWS * W);
        const int ch  = ph * 7 + dxl;
        out[((size_t)(b * 49 + ch) * T + t) * slice + (size_t)h0 * W + pos] =
            obuf0[m] + obuf1[m];
      }
    }
  }
}

}  // namespace

extern "C" void kernel_launch(void* const* d_in, const int* in_sizes, int n_in,
                              void* d_out, int out_size, void* d_ws, size_t ws_size,
                              hipStream_t stream) {
  const float* x  = (const float*)d_in[0];
  const float* fw = (const float*)d_in[1];
  float* out      = (float*)d_out;
  corr_fwd<<<NBLK, NTHR, 0, stream>>>(x, fw, out);
}

// Round 7
// 2022.585 us; speedup vs baseline: 1.0017x; 1.0017x over previous
//
#include <hip/hip_runtime.h>
#include <type_traits>

namespace {

constexpr int KK   = 7;
constexpr int PADC = 3;
constexpr int B = 8, C = 64, T = 32, H = 56, W = 56;

constexpr int ROWS = 8;                      // output rows per block
constexpr int HALF = 448;                    // threads per channel-half
constexpr int NTHR = 896;                    // 2 halves x (7 dy * 8 chunks * 8 rows)
constexpr int NBLK = B * T * (H / ROWS);     // 1792
constexpr int CH   = 32;                     // channels per half

// LDS layout (floats)
constexpr int X2_STRIDE = 132;               // 8 chunks*16 + 4 pad
constexpr int X2_ROWS   = ROWS + KK - 1;     // 14
constexpr int X2_SIZE   = X2_ROWS * X2_STRIDE;   // 1848
constexpr int X1_STRIDE = 68;                // 8 chunks*8 + 4 pad
constexpr int X1_SIZE   = ROWS * X1_STRIDE;  // 544
constexpr int CBUF      = X2_SIZE + X1_SIZE; // 2392 floats per channel
constexpr int W_SIZE    = C * 56;            // [c][dy*8+j], 3584
// weights + 2 halves x double-buffered channel buffer
constexpr int SMEM_FLOATS = W_SIZE + 4 * CBUF;   // 13152 floats = 52.6 KB

// Counted barrier: make LDS traffic visible without draining vmcnt.
__device__ inline void barrier_lgkm_only() {
  asm volatile("s_waitcnt lgkmcnt(0)" ::: "memory");
  __builtin_amdgcn_s_barrier();
  asm volatile("" ::: "memory");
}

// min 4 waves/EU = exactly ONE 896-thread block/CU -> VGPR cap 128.
// (R6: no 2nd arg -> hipcc targeted 2 blocks/CU -> VGPR 64 -> acc spilled
//  wholesale, 6.8 GB of scratch traffic. HW ran 1 block/CU regardless.)
__global__ __launch_bounds__(NTHR, 4)
void corr_fwd(const float* __restrict__ x, const float* __restrict__ fw,
              float* __restrict__ out) {
  __shared__ float smem[SMEM_FLOATS];
  float* w_s = smem;

  const int tid  = threadIdx.x;
  const int cg   = (tid >= HALF) ? 1 : 0;    // channel-half: waves 0-6 / 7-13
  const int ltid = tid - cg * HALF;
  const int dy   = ltid % 7;
  const int q    = (ltid / 7) % 8;
  const int r    = ltid / 56;

  int blk = blockIdx.x;
  const int rt = blk % (H / ROWS);
  blk /= (H / ROWS);
  const int t = blk % T;
  const int b = blk / T;
  const int h0 = rt * ROWS;
  const int tp = (t > 0) ? (t - 1) : 0;

  // ---- stage weights * (1/64) for all c, padded to 8 per (c,dy) row ----
  for (int sid = tid; sid < W_SIZE; sid += NTHR) {
    const int c   = sid / 56;
    const int rm  = sid - c * 56;
    const int dyw = rm >> 3;
    const int j   = rm & 7;
    float v = 0.f;
    if (j < 7) v = fw[((c * T + t) * KK + dyw) * KK + j] * (1.0f / 64.0f);
    w_s[sid] = v;
  }
  // ---- zero-init channel buffers once: halo slots rely on staying 0 ----
  for (int i = tid; i < 4 * CBUF; i += NTHR) smem[W_SIZE + i] = 0.f;

  // ---- staging coordinates (per half, hoisted); l<0 means "skip write" ----
  int g2[4], l2[4];
#pragma unroll
  for (int k = 0; k < 4; ++k) {
    const int sid = ltid + k * HALF;
    const int rr  = sid >> 7;
    const int qq  = (sid >> 4) & 7;
    const int j   = sid & 15;
    const int hg  = h0 + rr - PADC;
    const int wg  = qq * 7 + j - PADC;
    const bool ok = (hg >= 0) && (hg < H) && (wg >= 0) && (wg < W);
    g2[k] = ok ? (hg * W + wg) : 0;
    l2[k] = ok ? (rr * X2_STRIDE + qq * 16 + j) : -1;
  }
  int g1a, l1a;
  {
    const int rr = ltid >> 6, qq = (ltid >> 3) & 7, j = ltid & 7;
    const int wg = qq * 7 + j;
    g1a = (wg < W) ? ((h0 + rr) * W + wg) : 0;
    l1a = (wg < W) ? (rr * X1_STRIDE + qq * 8 + j) : -1;
  }
  const bool hasB = (ltid < 512 - HALF);     // wave 0 of each half: uniform
  int g1b = 0, l1b = -1;
  if (hasB) {
    const int sid = ltid + HALF;
    const int rr = sid >> 6, qq = (sid >> 3) & 7, j = sid & 7;
    const int wg = qq * 7 + j;
    g1b = (wg < W) ? ((h0 + rr) * W + wg) : 0;
    l1b = (wg < W) ? (rr * X1_STRIDE + qq * 8 + j) : -1;
  }

  float acc[7][7];
#pragma unroll
  for (int a = 0; a < 7; ++a)
#pragma unroll
    for (int e = 0; e < 7; ++e) acc[a][e] = 0.f;

  const size_t slice   = (size_t)H * W;        // 3136
  const size_t cstride = (size_t)T * slice;    // 100352
  // this half's channel range starts at cg*CH
  const float* n2 = x + ((size_t)(b * C + cg * CH) * T + t)  * slice;
  const float* n1 = x + ((size_t)(b * C + cg * CH) * T + tp) * slice;

  // ---- 3 register staging sets, 1 channel each (depth-3 SW pipeline) ----
  float S2[3][4], S1A[3], S1B[3];

  auto load_set = [&](auto SC) {
    constexpr int S = decltype(SC)::value;
#pragma unroll
    for (int k = 0; k < 4; ++k) S2[S][k] = n2[g2[k]];
    S1A[S] = n1[g1a];
    if (hasB) S1B[S] = n1[g1b];
    n2 += cstride;
    n1 += cstride;
  };
  auto write_set = [&](auto SC, float* x2s) {
    constexpr int S = decltype(SC)::value;
    float* x1s = x2s + X2_SIZE;
#pragma unroll
    for (int k = 0; k < 4; ++k)
      if (l2[k] >= 0) x2s[l2[k]] = S2[S][k];
    if (l1a >= 0) x1s[l1a] = S1A[S];
    if (hasB && l1b >= 0) x1s[l1b] = S1B[S];
  };
  auto compute1 = [&](const float* x2s, int c) {   // c = within-half channel
    const float* x1s = x2s + X2_SIZE;
    const float4* zp = reinterpret_cast<const float4*>(x2s + (r + dy) * X2_STRIDE + q * 16);
    const float4 z0 = zp[0], z1 = zp[1], z2v = zp[2], z3v = zp[3];
    const float4* xp = reinterpret_cast<const float4*>(x1s + r * X1_STRIDE + q * 8);
    const float4 xa = xp[0], xbv = xp[1];
    const float4* wp = reinterpret_cast<const float4*>(w_s + (cg * CH + c) * 56 + dy * 8);
    const float4 wa = wp[0], wbv = wp[1];

    const float zz[16] = {z0.x, z0.y, z0.z, z0.w,  z1.x, z1.y, z1.z, z1.w,
                          z2v.x, z2v.y, z2v.z, z2v.w,  z3v.x, z3v.y, z3v.z, z3v.w};
    const float xx[7]  = {xa.x, xa.y, xa.z, xa.w,  xbv.x, xbv.y, xbv.z};
    const float wv[7]  = {wa.x, wa.y, wa.z, wa.w,  wbv.x, wbv.y, wbv.z};

#pragma unroll
    for (int i = 0; i < 7; ++i)
#pragma unroll
      for (int dx = 0; dx < 7; ++dx)
        acc[dx][i] = fmaf(wv[dx], xx[i] * zz[i + dx], acc[dx][i]);
  };

  float* hbase = smem + W_SIZE + cg * (2 * CBUF);  // this half's buffers
  float* buf0 = hbase;
  float* buf1 = hbase + CBUF;

  auto stage = [&](auto SC, float* base, int c, bool doLoad) {
    write_set(SC, base);
    if (doLoad) load_set(SC);
    barrier_lgkm_only();
    compute1(base, c);
  };

  __syncthreads();  // zero-init + weights visible before first ds_writes

  // prologue: within-half channels 0,1,2
  load_set(std::integral_constant<int, 0>{});
  load_set(std::integral_constant<int, 1>{});
  load_set(std::integral_constant<int, 2>{});

  // stages 0..23 (all prefetch c+3 <= 26 valid)
  for (int bs = 0; bs < 24; bs += 6) {
    stage(std::integral_constant<int, 0>{}, buf0, bs + 0, true);
    stage(std::integral_constant<int, 1>{}, buf1, bs + 1, true);
    stage(std::integral_constant<int, 2>{}, buf0, bs + 2, true);
    stage(std::integral_constant<int, 0>{}, buf1, bs + 3, true);
    stage(std::integral_constant<int, 1>{}, buf0, bs + 4, true);
    stage(std::integral_constant<int, 2>{}, buf1, bs + 5, true);
  }
  // tail: stages 24..31 (prefetch while c+3 <= 31)
  stage(std::integral_constant<int, 0>{}, buf0, 24, true);   // loads 27
  stage(std::integral_constant<int, 1>{}, buf1, 25, true);   // loads 28
  stage(std::integral_constant<int, 2>{}, buf0, 26, true);   // loads 29
  stage(std::integral_constant<int, 0>{}, buf1, 27, true);   // loads 30
  stage(std::integral_constant<int, 1>{}, buf0, 28, true);   // loads 31
  stage(std::integral_constant<int, 2>{}, buf1, 29, false);
  stage(std::integral_constant<int, 0>{}, buf0, 30, false);
  stage(std::integral_constant<int, 1>{}, buf1, 31, false);

  // ---- epilogue: per-half LDS transpose + 2-term reduce, coalesced out ----
  float* obuf0 = smem;          // alias weights (3584 >= 3136)
  float* obuf1 = smem + 8000;   // alias buffer region (8000+3136 <= 13152)
#pragma unroll 1
  for (int ph = 0; ph < 7; ++ph) {
    __syncthreads();            // full barrier: prior reads/copies retired
    if (dy == ph) {
      float* ob = cg ? obuf1 : obuf0;
#pragma unroll
      for (int dx = 0; dx < 7; ++dx)
#pragma unroll
        for (int i = 0; i < 7; ++i)
          ob[dx * (ROWS * W) + r * W + q * 7 + i] = acc[dx][i];
    }
    __syncthreads();
#pragma unroll
    for (int mi = 0; mi < 4; ++mi) {
      const int m = tid + mi * NTHR;
      if (m < 7 * ROWS * W) {
        const int dxl = m / (ROWS * W);
        const int pos = m - dxl * (ROWS * W);
        const int ch  = ph * 7 + dxl;
        out[((size_t)(b * 49 + ch) * T + t) * slice + (size_t)h0 * W + pos] =
            obuf0[m] + obuf1[m];
      }
    }
  }
}

}  // namespace

extern "C" void kernel_launch(void* const* d_in, const int* in_sizes, int n_in,
                              void* d_out, int out_size, void* d_ws, size_t ws_size,
                              hipStream_t stream) {
  const float* x  = (const float*)d_in[0];
  const float* fw = (const float*)d_in[1];
  float* out      = (float*)d_out;
  corr_fwd<<<NBLK, NTHR, 0, stream>>>(x, fw, out);
}

// Round 8
// 378.275 us; speedup vs baseline: 5.3558x; 5.3469x over previous
//
#include <hip/hip_runtime.h>

namespace {

constexpr int KK   = 7;
constexpr int PADC = 3;
constexpr int B = 8, C = 64, T = 32, H = 56, W = 56;

constexpr int ROWS = 8;                       // output rows per block
constexpr int NTHR = 448;                     // 7 dy * 8 q-chunks * 8 rows
constexpr int NBLK = B * T * (H / ROWS);      // 1792
constexpr int SLICE = H * W;                  // 3136
constexpr int CSTRIDE = T * SLICE;            // 100352 (channel stride in x)
constexpr int WSTRIDE = T * KK * KK;          // 1568   (channel stride in fw)
constexpr int NTOT = B * C * CSTRIDE;         // total floats in x

// 4B-aligned float4: global loads at arbitrary dword offsets (windows start
// at col q*7-3, not 16B-aligned).
typedef float f4 __attribute__((ext_vector_type(4), aligned(4)));

// 2nd arg = 1: under either launch_bounds semantics (min-blocks or
// min-waves/EU) the VGPR cap stays >= 256. R6/R7 showed larger values
// shrink the cap (64!) and wholesale-spill the 49-reg accumulator.
__global__ __launch_bounds__(NTHR, 1)
void corr_fwd(const float* __restrict__ x, const float* __restrict__ fw,
              float* __restrict__ out) {
  __shared__ float obuf[KK * ROWS * W];   // 3136 floats, epilogue only

  const int tid = threadIdx.x;
  const int dy  = tid % 7;
  const int q   = (tid / 7) % 8;
  const int r   = tid / 56;

  int blk = blockIdx.x;
  const int rt = blk % (H / ROWS); blk /= (H / ROWS);
  const int t  = blk % T;
  const int b  = blk / T;
  const int h0 = rt * ROWS;
  const int tp = (t > 0) ? (t - 1) : 0;

  // per-thread geometry (channel-invariant, hoisted)
  const int  zrow_raw = h0 + r + dy - PADC;
  const bool row_ok   = (zrow_raw >= 0) && (zrow_raw < H);
  const int  zrow     = zrow_raw < 0 ? 0 : (zrow_raw >= H ? H - 1 : zrow_raw);
  const unsigned mlo  = (q == 0) ? 0u : ~0u;   // window cols -3..-1 invalid
  const unsigned mhi  = (q == 7) ? 0u : ~0u;   // window cols 56..58 invalid

  // rolling flat indices (int32: NTOT = 51.4M < 2^31)
  int zidx = (b * C * T + t)  * SLICE + zrow * W + q * 7 - PADC;
  int xidx = (b * C * T + tp) * SLICE + (h0 + r) * W + q * 7;
  int widx = (t * KK + dy) * KK;

  float acc[7][7];
#pragma unroll
  for (int a = 0; a < 7; ++a)
#pragma unroll
    for (int e = 0; e < 7; ++e) acc[a][e] = 0.f;

  // ---- register staging sets (depth-1 prefetch, named A/B: rule #20) ----
  f4 ZA[3], ZB[3]; float zA12, zB12;
  f4 XA[2], XB[2];
  f4 WAa, WAb, WBa, WBb;

  auto loadZfast = [&](f4 (&Z)[3], float& z12, int idx) {
    const f4* p = reinterpret_cast<const f4*>(x + idx);
    Z[0] = p[0]; Z[1] = p[1]; Z[2] = p[2];     // window cols q*7-3 .. q*7+8
    z12 = x[idx + 12];                          // col q*7+9
  };
  // c==0 (underflow at b=0,t=0,row0,q0) / c==63 (overflow at b=7,t=31,row55,q7)
  auto loadZsafe = [&](f4 (&Z)[3], float& z12, int idx) {
#pragma unroll
    for (int j = 0; j < 12; ++j) {
      int fi = idx + j;
      fi = fi < 0 ? 0 : (fi > NTOT - 1 ? NTOT - 1 : fi);
      Z[j / 4][j % 4] = x[fi];                  // static reg index (unrolled)
    }
    int fi = idx + 12;
    fi = fi < 0 ? 0 : (fi > NTOT - 1 ? NTOT - 1 : fi);
    z12 = x[fi];
  };
  auto loadX = [&](f4 (&X)[2], int idx) {       // always in-bounds (tp<=30)
    const f4* p = reinterpret_cast<const f4*>(x + idx);
    X[0] = p[0]; X[1] = p[1];
  };
  auto loadW = [&](f4& wa, f4& wb, int idx) {   // 7 w via overlapping f4
    wa = *reinterpret_cast<const f4*>(fw + idx);        // w[0..3]
    wb = *reinterpret_cast<const f4*>(fw + idx + 3);    // w[3..6]
  };
  auto maskf = [](float v, unsigned m) {
    return __uint_as_float(__float_as_uint(v) & m);
  };

  auto compute = [&](const f4 (&Z)[3], float z12, const f4 (&X)[2],
                     f4 wa, f4 wb) {
    if (row_ok) {   // exec-masked: OOB-row lanes keep acc == 0
      const float zz[13] = {
          maskf(Z[0][0], mlo), maskf(Z[0][1], mlo), maskf(Z[0][2], mlo),
          Z[0][3], Z[1][0], Z[1][1], Z[1][2], Z[1][3], Z[2][0], Z[2][1],
          maskf(Z[2][2], mhi), maskf(Z[2][3], mhi), maskf(z12, mhi)};
      const float xx[7] = {X[0][0], X[0][1], X[0][2], X[0][3],
                           X[1][0], X[1][1], X[1][2]};
      const float wv[7] = {wa[0], wa[1], wa[2], wa[3], wb[1], wb[2], wb[3]};
#pragma unroll
      for (int i = 0; i < 7; ++i)
#pragma unroll
        for (int dx = 0; dx < 7; ++dx)
          acc[dx][i] = fmaf(wv[dx], xx[i] * zz[i + dx], acc[dx][i]);
    }
  };

  // prologue: channel 0 -> A
  loadZsafe(ZA, zA12, zidx); loadX(XA, xidx); loadW(WAa, WAb, widx);
  zidx += CSTRIDE; xidx += CSTRIDE; widx += WSTRIDE;

  // main loop: NO barriers, NO LDS — loads of c+1 overlap compute of c.
  for (int cc = 0; cc < C; cc += 2) {
    // prefetch channel cc+1 -> B
    if (cc == C - 2) loadZsafe(ZB, zB12, zidx);
    else             loadZfast(ZB, zB12, zidx);
    loadX(XB, xidx); loadW(WBa, WBb, widx);
    zidx += CSTRIDE; xidx += CSTRIDE; widx += WSTRIDE;
    compute(ZA, zA12, XA, WAa, WAb);            // channel cc

    // prefetch channel cc+2 -> A (channels 2..62: fast path provably safe)
    if (cc + 2 < C) {
      loadZfast(ZA, zA12, zidx);
      loadX(XA, xidx); loadW(WAa, WAb, widx);
      zidx += CSTRIDE; xidx += CSTRIDE; widx += WSTRIDE;
    }
    compute(ZB, zB12, XB, WBa, WBb);            // channel cc+1
  }

  // ---- coalesced write-out via LDS transpose (7 phases); fold 1/64 ----
  const float s = 1.0f / 64.0f;
#pragma unroll 1
  for (int ph = 0; ph < 7; ++ph) {
    __syncthreads();
    if (dy == ph) {
#pragma unroll
      for (int dx = 0; dx < 7; ++dx)
#pragma unroll
        for (int i = 0; i < 7; ++i)
          obuf[(dx * ROWS + r) * W + q * 7 + i] = acc[dx][i] * s;
    }
    __syncthreads();
#pragma unroll
    for (int mi = 0; mi < 7; ++mi) {
      const int m   = tid + mi * NTHR;
      const int dxl = m / (ROWS * W);
      const int pos = m - dxl * (ROWS * W);
      const int ch  = ph * 7 + dxl;
      out[((size_t)(b * 49 + ch) * T + t) * SLICE + (size_t)h0 * W + pos] =
          obuf[m];
    }
  }
}

}  // namespace

extern "C" void kernel_launch(void* const* d_in, const int* in_sizes, int n_in,
                              void* d_out, int out_size, void* d_ws, size_t ws_size,
                              hipStream_t stream) {
  const float* x  = (const float*)d_in[0];
  const float* fw = (const float*)d_in[1];
  float* out      = (float*)d_out;
  corr_fwd<<<NBLK, NTHR, 0, stream>>>(x, fw, out);
}